// Round 4
// baseline (57.116 us; speedup 1.0000x reference)
//
#include <hip/hip_runtime.h>
#include <hip/hip_bf16.h>
#include <math.h>

#define BB 8
#define CC 128
#define NPTS 8192
#define KNBR 16

typedef __attribute__((ext_vector_type(8))) short bf16x8;
typedef __attribute__((ext_vector_type(4))) float f32x4;

__device__ __forceinline__ unsigned short f2bf(float f) {
    unsigned int u = __float_as_uint(f);
    unsigned int r = (u + 0x7fffu + ((u >> 16) & 1u)) >> 16;
    return (unsigned short)r;
}
__device__ __forceinline__ float bf2f(unsigned short h) {
    return __uint_as_float(((unsigned int)h) << 16);
}
__device__ __forceinline__ float lrelu(float v) { return v >= 0.0f ? v : 0.2f * v; }

// ---------------- Kernel 1: both hypernetworks -> W1,W2 [o][i] bf16 + per-block reg partials ----------------
__global__ void hyper_kernel(const float* __restrict__ fc11_w1, const float* __restrict__ fc11_b1,
                             const float* __restrict__ fc12_w1, const float* __restrict__ fc12_b1,
                             const float* __restrict__ fcsk_w1, const float* __restrict__ fcsk_b1,
                             const float* __restrict__ fc11_w2, const float* __restrict__ fc11_b2,
                             const float* __restrict__ fc12_w2, const float* __restrict__ fc12_b2,
                             const float* __restrict__ fcsk_w2, const float* __restrict__ fcsk_b2,
                             const int* __restrict__ up,
                             unsigned short* __restrict__ W1, unsigned short* __restrict__ W2,
                             float* __restrict__ regp) {
    int set = blockIdx.x >> 6;  // 0: W1 params, 1: W2 params
    const float* fc11_w = set ? fc11_w2 : fc11_w1;
    const float* fc11_b = set ? fc11_b2 : fc11_b1;
    const float* fc12_w = set ? fc12_w2 : fc12_w1;
    const float* fc12_b = set ? fc12_b2 : fc12_b1;
    const float* fcsk_w = set ? fcsk_w2 : fcsk_w1;
    const float* fcsk_b = set ? fcsk_b2 : fcsk_b1;
    unsigned short* W = set ? W2 : W1;

    __shared__ float h[32];
    __shared__ float red[256];
    int t = threadIdx.x;
    double us = (double)(*up);
    int idxq = (int)((us * us - 1.1) / 0.1);
    float s = (float)(sqrt(1.1 + 0.1 * (double)idxq) / sqrt(1.1 + 0.1 * 79.0));
    if (t < 32) h[t] = lrelu(fc11_w[t] * s + fc11_b[t]);
    __syncthreads();
    int j = (blockIdx.x & 63) * 256 + t;  // 0..16383 = o*128+i
    const float* wr = fc12_w + j * 32;
    float acc = fc12_b[j] + fcsk_w[j] * s + fcsk_b[j];
#pragma unroll
    for (int k = 0; k < 32; ++k) acc = fmaf(wr[k], h[k], acc);
    W[j] = f2bf(acc);  // natural [o][i] layout
    red[t] = acc * acc;
    __syncthreads();
    for (int st = 128; st > 0; st >>= 1) {
        if (t < st) red[t] += red[t + st];
        __syncthreads();
    }
    if (t == 0) regp[blockIdx.x] = 0.5f * red[0];  // plain store: deterministic, no memset needed
}

// ---------------- Kernel 2 (MFMA): out = W1@x/17 + x ; y2t = (W2@x)^T bf16 (coalesced) ----------------
// grid: BB * NPTS/64 blocks; block 256 = 4 waves; wave w owns o in [32w,32w+32)
__global__ __launch_bounds__(256, 3) void matmul_kernel(const float* __restrict__ points,
                                                        const unsigned short* __restrict__ W1,
                                                        const unsigned short* __restrict__ W2,
                                                        float* __restrict__ out,
                                                        unsigned short* __restrict__ y2t) {
    __shared__ float xf_s[128 * 68];                          // lrelu(x) tile f32 [i][n], stride 68
    __shared__ __align__(16) unsigned short xb_s[64 * 136];   // lrelu(x) bf16 [n][i]; reused as y2 stage

    int bid = blockIdx.x;
    int b = bid >> 7;
    int n0 = (bid & 127) * 64;
    int t = threadIdx.x;

    // stage: coalesced float4 reads along n; write f32 [i][n] + transposed bf16 [n][i]
#pragma unroll
    for (int iter = 0; iter < 8; ++iter) {
        int row = iter * 16 + (t >> 4);
        int c4 = (t & 15) * 4;
        float4 v = *(const float4*)(points + ((size_t)(b * CC + row)) * NPTS + n0 + c4);
        v.x = lrelu(v.x); v.y = lrelu(v.y); v.z = lrelu(v.z); v.w = lrelu(v.w);
        *(float4*)(xf_s + row * 68 + c4) = v;
        xb_s[(c4 + 0) * 136 + row] = f2bf(v.x);
        xb_s[(c4 + 1) * 136 + row] = f2bf(v.y);
        xb_s[(c4 + 2) * 136 + row] = f2bf(v.z);
        xb_s[(c4 + 3) * 136 + row] = f2bf(v.w);
    }
    __syncthreads();

    int w = t >> 6, l = t & 63;
    int g = l >> 4, ln = l & 15;
    int o_base = w * 32;

    f32x4 zero = {0.0f, 0.0f, 0.0f, 0.0f};
    f32x4 acc1[2][4], acc2[2][4];
#pragma unroll
    for (int ot = 0; ot < 2; ++ot)
#pragma unroll
        for (int nt = 0; nt < 4; ++nt) { acc1[ot][nt] = zero; acc2[ot][nt] = zero; }

#pragma unroll
    for (int ks = 0; ks < 4; ++ks) {
        int k0 = ks * 32;
        // A-frags (W) direct from global (L2-hot, 32KB each): lane l -> row o, k = k0 + 8g..+7
        bf16x8 wf1[2], wf2[2];
#pragma unroll
        for (int ot = 0; ot < 2; ++ot) {
            int orow = o_base + ot * 16 + ln;
            wf1[ot] = *(const bf16x8*)(W1 + orow * 128 + k0 + 8 * g);
            wf2[ot] = *(const bf16x8*)(W2 + orow * 128 + k0 + 8 * g);
        }
        // B-frags (x) from LDS: lane l -> col n = ln, k = k0 + 8g..+7 (contiguous b128)
        bf16x8 xv[4];
#pragma unroll
        for (int nt = 0; nt < 4; ++nt)
            xv[nt] = *(const bf16x8*)(xb_s + (nt * 16 + ln) * 136 + k0 + 8 * g);
#pragma unroll
        for (int ot = 0; ot < 2; ++ot)
#pragma unroll
            for (int nt = 0; nt < 4; ++nt) {
                acc1[ot][nt] = __builtin_amdgcn_mfma_f32_16x16x32_bf16(wf1[ot], xv[nt], acc1[ot][nt], 0, 0, 0);
                acc2[ot][nt] = __builtin_amdgcn_mfma_f32_16x16x32_bf16(wf2[ot], xv[nt], acc2[ot][nt], 0, 0, 0);
            }
    }

    const float inv17 = 1.0f / 17.0f;
    // D layout: col(n) = ln, row(o) = 4g + reg  [m89]
    // epilogue A: center conv + residual -> out (coalesced along n)
#pragma unroll
    for (int ot = 0; ot < 2; ++ot)
#pragma unroll
        for (int nt = 0; nt < 4; ++nt) {
            int n_loc = nt * 16 + ln;
            int o_lo = o_base + ot * 16 + 4 * g;
            float* op = out + ((size_t)(b * CC + o_lo)) * NPTS + n0 + n_loc;
#pragma unroll
            for (int r = 0; r < 4; ++r)
                op[(size_t)r * NPTS] = fmaf(acc1[ot][nt][r], inv17, xf_s[(o_lo + r) * 68 + n_loc]);
        }

    // epilogue B: stage acc2 (bf16) into LDS, then write y2t rows contiguously
    __syncthreads();  // all waves done reading xb_s
#pragma unroll
    for (int ot = 0; ot < 2; ++ot)
#pragma unroll
        for (int nt = 0; nt < 4; ++nt) {
            int n_loc = nt * 16 + ln;
            int o_lo = o_base + ot * 16 + 4 * g;
            ushort4 pk;
            pk.x = f2bf(acc2[ot][nt][0]);
            pk.y = f2bf(acc2[ot][nt][1]);
            pk.z = f2bf(acc2[ot][nt][2]);
            pk.w = f2bf(acc2[ot][nt][3]);
            *(ushort4*)(xb_s + n_loc * 136 + o_lo) = pk;
        }
    __syncthreads();
    // 64 rows x 256B, 16B per thread: fully coalesced dwordx4 stores
#pragma unroll
    for (int it = 0; it < 4; ++it) {
        int row = it * 16 + (t >> 4);
        int seg = t & 15;
        *(uint4*)(y2t + ((size_t)(b * NPTS + n0 + row)) * CC + seg * 8) =
            *(const uint4*)(xb_s + row * 136 + seg * 8);
    }
}

// ---------------- Kernel 3: out += (sum_k y2t[idx]) / 17 ; block 0 also reduces reg partials ----------------
// XCD-pinned: batch = blockIdx % 8 so each batch's 2MB y2t slice stays in one XCD's L2.
// Wave splits into two 32-lane halves: each half processes one index (4 ch/lane, uint2),
// halves combined with shfl_xor(32) -> 2 indices in flight per instruction.
__global__ __launch_bounds__(256) void gather_kernel(const unsigned short* __restrict__ y2t,
                                                     const int* __restrict__ indices,
                                                     float* __restrict__ out,
                                                     const float* __restrict__ regp,
                                                     float* __restrict__ reg_out) {
    __shared__ int idx_s[64][16];
    __shared__ __align__(16) float gbuf[64][132];
    int t = threadIdx.x;
    int bid = blockIdx.x;
    int b = bid & 7;
    int n0 = (bid >> 3) * 64;

#pragma unroll
    for (int iter = 0; iter < 4; ++iter) {
        int chunk = iter * 256 + t;
        idx_s[chunk >> 4][chunk & 15] = indices[((size_t)(b * NPTS + n0)) * KNBR + chunk];
    }
    __syncthreads();

    int w = t >> 6, l = t & 63;
    int half = l >> 5, l32 = l & 31;
    const unsigned short* ybase = y2t + (size_t)b * NPTS * CC + 4 * l32;
    for (int nn = w * 16; nn < w * 16 + 16; ++nn) {
        float s0 = 0.0f, s1 = 0.0f, s2 = 0.0f, s3 = 0.0f;
#pragma unroll
        for (int k = 0; k < KNBR; k += 2) {
            int j = idx_s[nn][k + half];
            uint2 u = *(const uint2*)(ybase + (size_t)j * CC);
            s0 += bf2f((unsigned short)(u.x & 0xffffu));
            s1 += bf2f((unsigned short)(u.x >> 16));
            s2 += bf2f((unsigned short)(u.y & 0xffffu));
            s3 += bf2f((unsigned short)(u.y >> 16));
        }
        s0 += __shfl_xor(s0, 32);
        s1 += __shfl_xor(s1, 32);
        s2 += __shfl_xor(s2, 32);
        s3 += __shfl_xor(s3, 32);
        if (half == 0) {
            float4 v = {s0, s1, s2, s3};
            *(float4*)&gbuf[nn][4 * l32] = v;
        }
    }
    __syncthreads();

    const float inv17 = 1.0f / 17.0f;
    // RMW phase: lane reads float4 of channels, 4 coalesced global RMWs
#pragma unroll
    for (int it = 0; it < 8; ++it) {
        int c0 = it * 16 + w * 4;
        float4 v = *(const float4*)&gbuf[l][c0];
        float vv[4] = {v.x, v.y, v.z, v.w};
#pragma unroll
        for (int r = 0; r < 4; ++r) {
            float* p = out + ((size_t)(b * CC + c0 + r)) * NPTS + n0 + l;
            *p += vv[r] * inv17;
        }
    }

    // fold the 128-partial reg-loss reduction into block 0 (one wave, shuffle only)
    if (bid == 0 && t < 64) {
        float v = regp[t] + regp[t + 64];
#pragma unroll
        for (int off = 32; off; off >>= 1) v += __shfl_down(v, off);
        if (t == 0) reg_out[0] = v;
    }
}

extern "C" void kernel_launch(void* const* d_in, const int* in_sizes, int n_in,
                              void* d_out, int out_size, void* d_ws, size_t ws_size,
                              hipStream_t stream) {
    const float* points = (const float*)d_in[0];
    const int* indices = (const int*)d_in[1];
    const int* up = (const int*)d_in[2];
    const float* fc11_w1 = (const float*)d_in[3];
    const float* fc11_b1 = (const float*)d_in[4];
    const float* fc12_w1 = (const float*)d_in[5];
    const float* fc12_b1 = (const float*)d_in[6];
    const float* fcsk_w1 = (const float*)d_in[7];
    const float* fcsk_b1 = (const float*)d_in[8];
    const float* fc11_w2 = (const float*)d_in[9];
    const float* fc11_b2 = (const float*)d_in[10];
    const float* fc12_w2 = (const float*)d_in[11];
    const float* fc12_b2 = (const float*)d_in[12];
    const float* fcsk_w2 = (const float*)d_in[13];
    const float* fcsk_b2 = (const float*)d_in[14];

    float* out = (float*)d_out;
    unsigned short* y2t = (unsigned short*)d_ws;  // 16 MB bf16 [B][N][C]
    unsigned short* W1 = (unsigned short*)((char*)d_ws + (size_t)BB * NPTS * CC * 2);
    unsigned short* W2 = W1 + CC * CC;
    float* regp = (float*)(W2 + CC * CC);  // 128 per-block partials
    float* reg_out = out + (size_t)BB * CC * NPTS;

    hyper_kernel<<<128, 256, 0, stream>>>(fc11_w1, fc11_b1, fc12_w1, fc12_b1, fcsk_w1, fcsk_b1,
                                          fc11_w2, fc11_b2, fc12_w2, fc12_b2, fcsk_w2, fcsk_b2,
                                          up, W1, W2, regp);
    matmul_kernel<<<BB * (NPTS / 64), 256, 0, stream>>>(points, W1, W2, out, y2t);
    gather_kernel<<<BB * (NPTS / 64), 256, 0, stream>>>(y2t, indices, out, regp, reg_out);
}

// Round 5
// 54.802 us; speedup vs baseline: 1.0422x; 1.0422x over previous
//
#include <hip/hip_runtime.h>
#include <hip/hip_bf16.h>
#include <math.h>

#define BB 8
#define CC 128
#define NPTS 8192
#define KNBR 16

typedef __attribute__((ext_vector_type(8))) short bf16x8;
typedef __attribute__((ext_vector_type(4))) float f32x4;

__device__ __forceinline__ unsigned short f2bf(float f) {
    unsigned int u = __float_as_uint(f);
    unsigned int r = (u + 0x7fffu + ((u >> 16) & 1u)) >> 16;
    return (unsigned short)r;
}
__device__ __forceinline__ float bf2f(unsigned short h) {
    return __uint_as_float(((unsigned int)h) << 16);
}
__device__ __forceinline__ float lrelu(float v) { return v >= 0.0f ? v : 0.2f * v; }

// ---------------- Kernel 1: both hypernetworks -> W1,W2 [o][i] bf16 + per-block reg partials ----------------
__global__ void hyper_kernel(const float* __restrict__ fc11_w1, const float* __restrict__ fc11_b1,
                             const float* __restrict__ fc12_w1, const float* __restrict__ fc12_b1,
                             const float* __restrict__ fcsk_w1, const float* __restrict__ fcsk_b1,
                             const float* __restrict__ fc11_w2, const float* __restrict__ fc11_b2,
                             const float* __restrict__ fc12_w2, const float* __restrict__ fc12_b2,
                             const float* __restrict__ fcsk_w2, const float* __restrict__ fcsk_b2,
                             const int* __restrict__ up,
                             unsigned short* __restrict__ W1, unsigned short* __restrict__ W2,
                             float* __restrict__ regp) {
    int set = blockIdx.x >> 6;  // 0: W1 params, 1: W2 params
    const float* fc11_w = set ? fc11_w2 : fc11_w1;
    const float* fc11_b = set ? fc11_b2 : fc11_b1;
    const float* fc12_w = set ? fc12_w2 : fc12_w1;
    const float* fc12_b = set ? fc12_b2 : fc12_b1;
    const float* fcsk_w = set ? fcsk_w2 : fcsk_w1;
    const float* fcsk_b = set ? fcsk_b2 : fcsk_b1;
    unsigned short* W = set ? W2 : W1;

    __shared__ float h[32];
    __shared__ float red[256];
    int t = threadIdx.x;
    double us = (double)(*up);
    int idxq = (int)((us * us - 1.1) / 0.1);
    float s = (float)(sqrt(1.1 + 0.1 * (double)idxq) / sqrt(1.1 + 0.1 * 79.0));
    if (t < 32) h[t] = lrelu(fc11_w[t] * s + fc11_b[t]);
    __syncthreads();
    int j = (blockIdx.x & 63) * 256 + t;  // 0..16383 = o*128+i
    const float* wr = fc12_w + j * 32;
    float acc = fc12_b[j] + fcsk_w[j] * s + fcsk_b[j];
#pragma unroll
    for (int k = 0; k < 32; ++k) acc = fmaf(wr[k], h[k], acc);
    W[j] = f2bf(acc);  // natural [o][i] layout
    red[t] = acc * acc;
    __syncthreads();
    for (int st = 128; st > 0; st >>= 1) {
        if (t < st) red[t] += red[t + st];
        __syncthreads();
    }
    if (t == 0) regp[blockIdx.x] = 0.5f * red[0];  // plain store: deterministic, no memset needed
}

// ---------------- Kernel 2 (MFMA): out = W1@x/17 + x ; y2t = (W2@x)^T bf16 ----------------
// grid: BB * NPTS/64 blocks; block 256 = 4 waves; wave w owns o in [32w,32w+32)
__global__ __launch_bounds__(256, 3) void matmul_kernel(const float* __restrict__ points,
                                                        const unsigned short* __restrict__ W1,
                                                        const unsigned short* __restrict__ W2,
                                                        float* __restrict__ out,
                                                        unsigned short* __restrict__ y2t) {
    __shared__ float xf_s[128 * 68];           // lrelu(x) tile f32 [i][n], stride 68
    __shared__ unsigned short xb_s[64 * 136];  // lrelu(x) tile bf16 [n][i], stride 136

    int bid = blockIdx.x;
    int b = bid >> 7;
    int n0 = (bid & 127) * 64;
    int t = threadIdx.x;

    // stage: coalesced float4 reads along n; write f32 [i][n] + transposed bf16 [n][i]
#pragma unroll
    for (int iter = 0; iter < 8; ++iter) {
        int row = iter * 16 + (t >> 4);
        int c4 = (t & 15) * 4;
        float4 v = *(const float4*)(points + ((size_t)(b * CC + row)) * NPTS + n0 + c4);
        v.x = lrelu(v.x); v.y = lrelu(v.y); v.z = lrelu(v.z); v.w = lrelu(v.w);
        *(float4*)(xf_s + row * 68 + c4) = v;
        xb_s[(c4 + 0) * 136 + row] = f2bf(v.x);
        xb_s[(c4 + 1) * 136 + row] = f2bf(v.y);
        xb_s[(c4 + 2) * 136 + row] = f2bf(v.z);
        xb_s[(c4 + 3) * 136 + row] = f2bf(v.w);
    }
    __syncthreads();

    int w = t >> 6, l = t & 63;
    int g = l >> 4, ln = l & 15;
    int o_base = w * 32;

    f32x4 zero = {0.0f, 0.0f, 0.0f, 0.0f};
    f32x4 acc1[2][4], acc2[2][4];
#pragma unroll
    for (int ot = 0; ot < 2; ++ot)
#pragma unroll
        for (int nt = 0; nt < 4; ++nt) { acc1[ot][nt] = zero; acc2[ot][nt] = zero; }

#pragma unroll
    for (int ks = 0; ks < 4; ++ks) {
        int k0 = ks * 32;
        // A-frags (W) direct from global (L2-hot, 32KB each): lane l -> row o, k = k0 + 8g..+7
        bf16x8 wf1[2], wf2[2];
#pragma unroll
        for (int ot = 0; ot < 2; ++ot) {
            int orow = o_base + ot * 16 + ln;
            wf1[ot] = *(const bf16x8*)(W1 + orow * 128 + k0 + 8 * g);
            wf2[ot] = *(const bf16x8*)(W2 + orow * 128 + k0 + 8 * g);
        }
        // B-frags (x) from LDS: lane l -> col n = ln, k = k0 + 8g..+7 (contiguous b128)
        bf16x8 xv[4];
#pragma unroll
        for (int nt = 0; nt < 4; ++nt)
            xv[nt] = *(const bf16x8*)(xb_s + (nt * 16 + ln) * 136 + k0 + 8 * g);
#pragma unroll
        for (int ot = 0; ot < 2; ++ot)
#pragma unroll
            for (int nt = 0; nt < 4; ++nt) {
                acc1[ot][nt] = __builtin_amdgcn_mfma_f32_16x16x32_bf16(wf1[ot], xv[nt], acc1[ot][nt], 0, 0, 0);
                acc2[ot][nt] = __builtin_amdgcn_mfma_f32_16x16x32_bf16(wf2[ot], xv[nt], acc2[ot][nt], 0, 0, 0);
            }
    }

    const float inv17 = 1.0f / 17.0f;
    // D layout: col(n) = ln, row(o) = 4g + reg  [m89]
#pragma unroll
    for (int ot = 0; ot < 2; ++ot)
#pragma unroll
        for (int nt = 0; nt < 4; ++nt) {
            int n_loc = nt * 16 + ln;
            int o_lo = o_base + ot * 16 + 4 * g;
            float* op = out + ((size_t)(b * CC + o_lo)) * NPTS + n0 + n_loc;
#pragma unroll
            for (int r = 0; r < 4; ++r)
                op[(size_t)r * NPTS] = fmaf(acc1[ot][nt][r], inv17, xf_s[(o_lo + r) * 68 + n_loc]);
            ushort4 pk;
            pk.x = f2bf(acc2[ot][nt][0]);
            pk.y = f2bf(acc2[ot][nt][1]);
            pk.z = f2bf(acc2[ot][nt][2]);
            pk.w = f2bf(acc2[ot][nt][3]);
            *(ushort4*)(y2t + ((size_t)(b * NPTS + n0 + n_loc)) * CC + o_lo) = pk;
        }
}

// ---------------- Kernel 3: out += (sum_k y2t[idx]) / 17 ; block 0 also reduces reg partials ----------------
// XCD-pinned: batch = blockIdx % 8 so each batch's 2MB y2t slice stays in one XCD's L2
__global__ __launch_bounds__(256) void gather_kernel(const unsigned short* __restrict__ y2t,
                                                     const int* __restrict__ indices,
                                                     float* __restrict__ out,
                                                     const float* __restrict__ regp,
                                                     float* __restrict__ reg_out) {
    __shared__ int idx_s[64][16];
    __shared__ float gbuf[64][134];
    int t = threadIdx.x;
    int bid = blockIdx.x;
    int b = bid & 7;
    int n0 = (bid >> 3) * 64;

#pragma unroll
    for (int iter = 0; iter < 4; ++iter) {
        int chunk = iter * 256 + t;
        idx_s[chunk >> 4][chunk & 15] = indices[((size_t)(b * NPTS + n0)) * KNBR + chunk];
    }
    __syncthreads();

    int w = t >> 6, l = t & 63;
    const unsigned short* ybase = y2t + (size_t)b * NPTS * CC + 2 * l;
    for (int nn = w * 16; nn < w * 16 + 16; ++nn) {
        float s0 = 0.0f, s1 = 0.0f;
#pragma unroll
        for (int k = 0; k < KNBR; ++k) {
            int j = idx_s[nn][k];
            unsigned int u = *(const unsigned int*)(ybase + (size_t)j * CC);
            s0 += bf2f((unsigned short)(u & 0xffffu));
            s1 += bf2f((unsigned short)(u >> 16));
        }
        gbuf[nn][2 * l] = s0;
        gbuf[nn][2 * l + 1] = s1;
    }
    __syncthreads();

    const float inv17 = 1.0f / 17.0f;
#pragma unroll 4
    for (int iter = 0; iter < 32; ++iter) {
        int c = iter * 4 + w;
        float* p = out + ((size_t)(b * CC + c)) * NPTS + n0 + l;
        *p += gbuf[l][c] * inv17;
    }

    // fold the 128-partial reg-loss reduction into block 0 (one wave, shuffle only)
    if (bid == 0 && t < 64) {
        float v = regp[t] + regp[t + 64];
#pragma unroll
        for (int off = 32; off; off >>= 1) v += __shfl_down(v, off);
        if (t == 0) reg_out[0] = v;
    }
}

extern "C" void kernel_launch(void* const* d_in, const int* in_sizes, int n_in,
                              void* d_out, int out_size, void* d_ws, size_t ws_size,
                              hipStream_t stream) {
    const float* points = (const float*)d_in[0];
    const int* indices = (const int*)d_in[1];
    const int* up = (const int*)d_in[2];
    const float* fc11_w1 = (const float*)d_in[3];
    const float* fc11_b1 = (const float*)d_in[4];
    const float* fc12_w1 = (const float*)d_in[5];
    const float* fc12_b1 = (const float*)d_in[6];
    const float* fcsk_w1 = (const float*)d_in[7];
    const float* fcsk_b1 = (const float*)d_in[8];
    const float* fc11_w2 = (const float*)d_in[9];
    const float* fc11_b2 = (const float*)d_in[10];
    const float* fc12_w2 = (const float*)d_in[11];
    const float* fc12_b2 = (const float*)d_in[12];
    const float* fcsk_w2 = (const float*)d_in[13];
    const float* fcsk_b2 = (const float*)d_in[14];

    float* out = (float*)d_out;
    unsigned short* y2t = (unsigned short*)d_ws;  // 16 MB bf16 [B][N][C]
    unsigned short* W1 = (unsigned short*)((char*)d_ws + (size_t)BB * NPTS * CC * 2);
    unsigned short* W2 = W1 + CC * CC;
    float* regp = (float*)(W2 + CC * CC);  // 128 per-block partials
    float* reg_out = out + (size_t)BB * CC * NPTS;

    hyper_kernel<<<128, 256, 0, stream>>>(fc11_w1, fc11_b1, fc12_w1, fc12_b1, fcsk_w1, fcsk_b1,
                                          fc11_w2, fc11_b2, fc12_w2, fc12_b2, fcsk_w2, fcsk_b2,
                                          up, W1, W2, regp);
    matmul_kernel<<<BB * (NPTS / 64), 256, 0, stream>>>(points, W1, W2, out, y2t);
    gather_kernel<<<BB * (NPTS / 64), 256, 0, stream>>>(y2t, indices, out, regp, reg_out);
}